// Round 1
// baseline (640.944 us; speedup 1.0000x reference)
//
#include <hip/hip_runtime.h>

#define TT 2048
#define DM 1024
#define HPAD 2816
#define HID 2730

typedef __attribute__((ext_vector_type(4))) float f32x4;
typedef __attribute__((ext_vector_type(8))) short bf16x8;

static __device__ __forceinline__ float bf2f(short u) {
    union { float f; unsigned int i; } c; c.i = ((unsigned int)(unsigned short)u) << 16; return c.f;
}
static __device__ __forceinline__ short f2bf(float f) {
    union { float f; unsigned int i; } c; c.f = f;
    unsigned int i = c.i;
    unsigned int r = (i + 0x7fffu + ((i >> 16) & 1u)) >> 16;
    return (short)r;
}

static __device__ __forceinline__ void gload_lds16(const void* g, void* l) {
    __builtin_amdgcn_global_load_lds(
        (const __attribute__((address_space(1))) unsigned int*)g,
        (__attribute__((address_space(3))) unsigned int*)l, 16, 0, 0);
}

// ---------------- weight transpose + cast (+pad): in f32 [K,N] -> out bf16 [Npad,Kpad]
__global__ __launch_bounds__(256) void wprep(const float* __restrict__ in, short* __restrict__ out,
                                             int K, int N, int Kpad, int Npad) {
    __shared__ float tile[32][33];
    int kb = blockIdx.x * 32, nb = blockIdx.y * 32;
    int tx = threadIdx.x, ty = threadIdx.y; // 32 x 8
    #pragma unroll
    for (int i = 0; i < 32; i += 8) {
        int k = kb + ty + i, n = nb + tx;
        float v = (k < K && n < N) ? in[(size_t)k * N + n] : 0.f;
        tile[tx][ty + i] = v;
    }
    __syncthreads();
    #pragma unroll
    for (int i = 0; i < 32; i += 8) {
        int n = nb + ty + i, k = kb + tx;
        if (n < Npad && k < Kpad) out[(size_t)n * Kpad + k] = f2bf(tile[ty + i][tx]);
    }
}

// ---------------- fused double RMSNorm: x f32 [8192,1024] -> xn1, xn2 bf16
__global__ __launch_bounds__(256) void rmsnorm2(const float* __restrict__ x,
    const float* __restrict__ g1, const float* __restrict__ g2,
    short* __restrict__ xn1, short* __restrict__ xn2) {
    int row = blockIdx.x;
    const float* xr = x + (size_t)row * DM;
    int t = threadIdx.x;
    float4 v = ((const float4*)xr)[t];
    float ss = v.x*v.x + v.y*v.y + v.z*v.z + v.w*v.w;
    #pragma unroll
    for (int off = 1; off < 64; off <<= 1) ss += __shfl_xor(ss, off);
    __shared__ float red[4];
    if ((t & 63) == 0) red[t >> 6] = ss;
    __syncthreads();
    float tot = red[0] + red[1] + red[2] + red[3];
    float rs = rsqrtf(tot * (1.0f / DM) + 1e-6f);
    float4 G1 = ((const float4*)g1)[t];
    float4 G2 = ((const float4*)g2)[t];
    union { short s[4]; int2 v; } o1, o2;
    o1.s[0] = f2bf(v.x * rs * G1.x); o1.s[1] = f2bf(v.y * rs * G1.y);
    o1.s[2] = f2bf(v.z * rs * G1.z); o1.s[3] = f2bf(v.w * rs * G1.w);
    o2.s[0] = f2bf(v.x * rs * G2.x); o2.s[1] = f2bf(v.y * rs * G2.y);
    o2.s[2] = f2bf(v.z * rs * G2.z); o2.s[3] = f2bf(v.w * rs * G2.w);
    *(int2*)(xn1 + (size_t)row * DM + t * 4) = o1.v;
    *(int2*)(xn2 + (size_t)row * DM + t * 4) = o2.v;
}

// ---------------- bf16 MFMA GEMM: A[M,K] bf16, Bt[N,K] bf16 (transposed), 128x128 tile, BK=64
// EPI: 0 = Cb = acc (bf16); 1 = Of = X + acc (f32); 2 = Cb = silu(acc) (bf16);
//      3 = Cb *= acc (bf16 RMW); 4 = Of += acc (f32 RMW)
template<int EPI>
__global__ __launch_bounds__(256) void gemm_bt(
    const short* __restrict__ A, const short* __restrict__ Bt,
    short* __restrict__ Cb, const float* __restrict__ X, float* __restrict__ Of,
    int M, int N, int K)
{
    __shared__ short As[128 * 64];
    __shared__ short Bs[128 * 64];
    int t = threadIdx.x;
    int wid = t >> 6, l = t & 63;
    int wm = wid >> 1, wn = wid & 1;

    int nwg = gridDim.x, bid = blockIdx.x;
    int wg = (bid & 7) * (nwg >> 3) + (bid >> 3);   // XCD swizzle (all grids %8==0)
    int tiles_n = N >> 7;
    int tm = wg / tiles_n, tn = wg % tiles_n;

    const short* Arow = A + (size_t)(tm * 128) * K;
    const short* Brow = Bt + (size_t)(tn * 128) * K;

    f32x4 acc[4][4];
    #pragma unroll
    for (int m = 0; m < 4; m++)
        #pragma unroll
        for (int n = 0; n < 4; n++) acc[m][n] = (f32x4){0.f, 0.f, 0.f, 0.f};

    for (int kt = 0; kt < K; kt += 64) {
        __syncthreads();
        #pragma unroll
        for (int i = 0; i < 4; i++) {
            int linear = i * 256 + t;         // 0..1023
            int row = linear >> 3;            // 0..127
            int slot = linear & 7;
            int srcslot = slot ^ (row & 7);   // pre-swizzled source, linear LDS dest
            gload_lds16(Arow + (size_t)row * K + kt + srcslot * 8, (char*)As + linear * 16);
            gload_lds16(Brow + (size_t)row * K + kt + srcslot * 8, (char*)Bs + linear * 16);
        }
        __syncthreads();
        #pragma unroll
        for (int ks = 0; ks < 2; ks++) {
            bf16x8 af[4], bfr[4];
            #pragma unroll
            for (int m = 0; m < 4; m++) {
                int row = wm * 64 + m * 16 + (l & 15);
                af[m] = *(const bf16x8*)((char*)As + row * 128 + ((ks * 64 + (l >> 4) * 16) ^ ((row & 7) << 4)));
            }
            #pragma unroll
            for (int n = 0; n < 4; n++) {
                int row = wn * 64 + n * 16 + (l & 15);
                bfr[n] = *(const bf16x8*)((char*)Bs + row * 128 + ((ks * 64 + (l >> 4) * 16) ^ ((row & 7) << 4)));
            }
            #pragma unroll
            for (int m = 0; m < 4; m++)
                #pragma unroll
                for (int n = 0; n < 4; n++)
                    acc[m][n] = __builtin_amdgcn_mfma_f32_16x16x32_bf16(af[m], bfr[n], acc[m][n], 0, 0, 0);
        }
    }

    #pragma unroll
    for (int m = 0; m < 4; m++)
        #pragma unroll
        for (int n = 0; n < 4; n++)
            #pragma unroll
            for (int r = 0; r < 4; r++) {
                int row = tm * 128 + wm * 64 + m * 16 + (l >> 4) * 4 + r;
                int col = tn * 128 + wn * 64 + n * 16 + (l & 15);
                size_t idx = (size_t)row * N + col;
                float v = acc[m][n][r];
                if constexpr (EPI == 0) Cb[idx] = f2bf(v);
                else if constexpr (EPI == 1) Of[idx] = X[idx] + v;
                else if constexpr (EPI == 2) Cb[idx] = f2bf(v * (1.f / (1.f + __expf(-v))));
                else if constexpr (EPI == 3) Cb[idx] = f2bf(bf2f(Cb[idx]) * v);
                else if constexpr (EPI == 4) Of[idx] += v;
            }
}

// ---------------- causal flash attention: qkv bf16 [B*T,3072] -> y bf16 [B*T,1024]
__global__ __launch_bounds__(256) void attn(const short* __restrict__ qkv, short* __restrict__ y) {
    __shared__ short Ks[64 * 64];
    __shared__ short Vt[64 * 64];
    __shared__ short Ps[4][16 * 72];
    int bh = blockIdx.y;
    int b = bh >> 4, h = bh & 15;
    int qt = blockIdx.x;
    int t = threadIdx.x, wid = t >> 6, l = t & 63;
    const size_t base = (size_t)b * TT * 3072;
    int q0 = qt * 64 + wid * 16;

    bf16x8 qf[2];
    #pragma unroll
    for (int s = 0; s < 2; s++) {
        int row = q0 + (l & 15);
        qf[s] = *(const bf16x8*)(qkv + base + (size_t)row * 3072 + h * 64 + s * 32 + (l >> 4) * 8);
    }

    f32x4 o[4];
    #pragma unroll
    for (int n = 0; n < 4; n++) o[n] = (f32x4){0.f, 0.f, 0.f, 0.f};
    float m[4], ll[4];
    #pragma unroll
    for (int r = 0; r < 4; r++) { m[r] = -1e30f; ll[r] = 0.f; }

    int kend = qt * 64 + 64;
    for (int kb = 0; kb < kend; kb += 64) {
        __syncthreads();   // protect prev-iter LDS reads
        #pragma unroll
        for (int i = 0; i < 2; i++) {
            int linear = i * 256 + t;     // 0..511
            int row = linear >> 3;        // kv 0..63
            int ch = linear & 7;
            int srcslot = ch ^ (row & 7);
            // K tile: swizzled source -> linear LDS (async)
            gload_lds16(qkv + base + (size_t)(kb + row) * 3072 + 1024 + h * 64 + srcslot * 8,
                        (char*)Ks + linear * 16);
            // V tile: manual transpose with swizzle
            uint4 vv = *(const uint4*)(qkv + base + (size_t)(kb + row) * 3072 + 2048 + h * 64 + ch * 8);
            const short* vs = (const short*)&vv;
            #pragma unroll
            for (int j = 0; j < 8; j++) {
                int d = ch * 8 + j;
                int byte = (d * 128 + row * 2) ^ ((d & 7) << 4);
                *(short*)((char*)Vt + byte) = vs[j];
            }
        }
        __syncthreads();

        // S = Q K^T  (rows=q, cols=kv)
        f32x4 s4[4];
        #pragma unroll
        for (int j = 0; j < 4; j++) {
            f32x4 z = (f32x4){0.f, 0.f, 0.f, 0.f};
            #pragma unroll
            for (int ks = 0; ks < 2; ks++) {
                int row = j * 16 + (l & 15);
                bf16x8 kf = *(const bf16x8*)((char*)Ks + row * 128 + ((ks * 64 + (l >> 4) * 16) ^ ((row & 7) << 4)));
                z = __builtin_amdgcn_mfma_f32_16x16x32_bf16(qf[ks], kf, z, 0, 0, 0);
            }
            s4[j] = z;
        }
        bool diag = (kb + 63 > q0);
        #pragma unroll
        for (int j = 0; j < 4; j++)
            #pragma unroll
            for (int r = 0; r < 4; r++) {
                float v = s4[j][r] * 0.125f;
                if (diag) {
                    int qrow = q0 + (l >> 4) * 4 + r;
                    int kcol = kb + j * 16 + (l & 15);
                    if (kcol > qrow) v = -1e30f;
                }
                s4[j][r] = v;
            }

        // online softmax (row stats live per reg r, reduced over 16-lane col groups)
        float alpha[4];
        #pragma unroll
        for (int r = 0; r < 4; r++) {
            float mx = fmaxf(fmaxf(s4[0][r], s4[1][r]), fmaxf(s4[2][r], s4[3][r]));
            #pragma unroll
            for (int off = 1; off < 16; off <<= 1) mx = fmaxf(mx, __shfl_xor(mx, off));
            float mn = fmaxf(m[r], mx);
            float a = __expf(m[r] - mn);
            float rs = 0.f;
            #pragma unroll
            for (int j = 0; j < 4; j++) {
                float p = __expf(s4[j][r] - mn);
                s4[j][r] = p;
                rs += p;
            }
            #pragma unroll
            for (int off = 1; off < 16; off <<= 1) rs += __shfl_xor(rs, off);
            ll[r] = ll[r] * a + rs;
            m[r] = mn;
            alpha[r] = a;
        }
        #pragma unroll
        for (int n = 0; n < 4; n++)
            #pragma unroll
            for (int r = 0; r < 4; r++) o[n][r] *= alpha[r];

        // P -> LDS (wave-private), then PV
        short* P = &Ps[wid][0];
        #pragma unroll
        for (int j = 0; j < 4; j++)
            #pragma unroll
            for (int r = 0; r < 4; r++)
                P[((l >> 4) * 4 + r) * 72 + j * 16 + (l & 15)] = f2bf(s4[j][r]);

        bf16x8 pf[2];
        #pragma unroll
        for (int ks = 0; ks < 2; ks++)
            pf[ks] = *(const bf16x8*)(P + (l & 15) * 72 + ks * 32 + (l >> 4) * 8);
        #pragma unroll
        for (int n = 0; n < 4; n++) {
            #pragma unroll
            for (int ks = 0; ks < 2; ks++) {
                int vrow = n * 16 + (l & 15);
                bf16x8 vf = *(const bf16x8*)((char*)Vt + vrow * 128 + ((ks * 64 + (l >> 4) * 16) ^ ((vrow & 7) << 4)));
                o[n] = __builtin_amdgcn_mfma_f32_16x16x32_bf16(pf[ks], vf, o[n], 0, 0, 0);
            }
        }
    }

    float inv[4];
    #pragma unroll
    for (int r = 0; r < 4; r++) inv[r] = 1.f / ll[r];
    #pragma unroll
    for (int n = 0; n < 4; n++)
        #pragma unroll
        for (int r = 0; r < 4; r++) {
            int row = q0 + (l >> 4) * 4 + r;
            int col = h * 64 + n * 16 + (l & 15);
            y[(size_t)(b * TT + row) * DM + col] = f2bf(o[n][r] * inv[r]);
        }
}

extern "C" void kernel_launch(void* const* d_in, const int* in_sizes, int n_in,
                              void* d_out, int out_size, void* d_ws, size_t ws_size,
                              hipStream_t stream) {
    (void)in_sizes; (void)n_in; (void)out_size; (void)ws_size;
    const float* x      = (const float*)d_in[0];
    const float* w_attn = (const float*)d_in[1];
    const float* w_proj = (const float*)d_in[2];
    const float* w1     = (const float*)d_in[3];
    const float* w2     = (const float*)d_in[4];
    const float* w3     = (const float*)d_in[5];
    const float* g1     = (const float*)d_in[6];
    const float* g2     = (const float*)d_in[7];
    float* out = (float*)d_out;

    char* ws = (char*)d_ws;
    size_t off = 0;
    auto alloc = [&](size_t bytes) { char* p = ws + off; off += (bytes + 255) & ~(size_t)255; return p; };
    short* wattn_t = (short*)alloc((size_t)3072 * 1024 * 2);
    short* wproj_t = (short*)alloc((size_t)1024 * 1024 * 2);
    short* w1t     = (short*)alloc((size_t)HPAD * 1024 * 2);
    short* w2t     = (short*)alloc((size_t)HPAD * 1024 * 2);
    short* w3t     = (short*)alloc((size_t)1024 * HPAD * 2);
    short* xn1     = (short*)alloc((size_t)8192 * 1024 * 2);
    short* xn2     = (short*)alloc((size_t)8192 * 1024 * 2);
    short* qkvb    = (short*)alloc((size_t)8192 * 3072 * 2);
    short* yb      = (short*)alloc((size_t)8192 * 1024 * 2);
    short* hb      = (short*)alloc((size_t)8192 * HPAD * 2);

    dim3 tb(32, 8);
    wprep<<<dim3(32, 96), tb, 0, stream>>>(w_attn, wattn_t, 1024, 3072, 1024, 3072);
    wprep<<<dim3(32, 32), tb, 0, stream>>>(w_proj, wproj_t, 1024, 1024, 1024, 1024);
    wprep<<<dim3(32, 88), tb, 0, stream>>>(w1, w1t, 1024, HID, 1024, HPAD);
    wprep<<<dim3(32, 88), tb, 0, stream>>>(w2, w2t, 1024, HID, 1024, HPAD);
    wprep<<<dim3(88, 32), tb, 0, stream>>>(w3, w3t, HID, 1024, HPAD, 1024);

    rmsnorm2<<<8192, 256, 0, stream>>>(x, g1, g2, xn1, xn2);

    gemm_bt<0><<<1536, 256, 0, stream>>>(xn1, wattn_t, qkvb, nullptr, nullptr, 8192, 3072, 1024);
    attn<<<dim3(32, 64), 256, 0, stream>>>(qkvb, yb);
    gemm_bt<1><<<512, 256, 0, stream>>>(yb, wproj_t, nullptr, x, out, 8192, 1024, 1024);
    gemm_bt<2><<<1408, 256, 0, stream>>>(xn2, w1t, hb, nullptr, nullptr, 8192, HPAD, 1024);
    gemm_bt<3><<<1408, 256, 0, stream>>>(xn2, w2t, hb, nullptr, nullptr, 8192, HPAD, 1024);
    gemm_bt<4><<<512, 256, 0, stream>>>(hb, w3t, nullptr, nullptr, out, 8192, 1024, HPAD);
}

// Round 2
// 590.812 us; speedup vs baseline: 1.0849x; 1.0849x over previous
//
#include <hip/hip_runtime.h>

#define TT 2048
#define DM 1024
#define HPAD 2816
#define HID 2730

typedef __attribute__((ext_vector_type(4))) float f32x4;
typedef __attribute__((ext_vector_type(8))) short bf16x8;

static __device__ __forceinline__ float bf2f(short u) {
    union { float f; unsigned int i; } c; c.i = ((unsigned int)(unsigned short)u) << 16; return c.f;
}
static __device__ __forceinline__ short f2bf(float f) {
    union { float f; unsigned int i; } c; c.f = f;
    unsigned int i = c.i;
    unsigned int r = (i + 0x7fffu + ((i >> 16) & 1u)) >> 16;
    return (short)r;
}

static __device__ __forceinline__ void gload_lds16(const void* g, void* l) {
    __builtin_amdgcn_global_load_lds(
        (const __attribute__((address_space(1))) unsigned int*)g,
        (__attribute__((address_space(3))) unsigned int*)l, 16, 0, 0);
}

// ---------------- weight transpose + cast (+pad): in f32 [K,N] -> out bf16 [Npad,Kpad]
__global__ __launch_bounds__(256) void wprep(const float* __restrict__ in, short* __restrict__ out,
                                             int K, int N, int Kpad, int Npad) {
    __shared__ float tile[32][33];
    int kb = blockIdx.x * 32, nb = blockIdx.y * 32;
    int tx = threadIdx.x, ty = threadIdx.y; // 32 x 8
    #pragma unroll
    for (int i = 0; i < 32; i += 8) {
        int k = kb + ty + i, n = nb + tx;
        float v = (k < K && n < N) ? in[(size_t)k * N + n] : 0.f;
        tile[tx][ty + i] = v;
    }
    __syncthreads();
    #pragma unroll
    for (int i = 0; i < 32; i += 8) {
        int n = nb + ty + i, k = kb + tx;
        if (n < Npad && k < Kpad) out[(size_t)n * Kpad + k] = f2bf(tile[ty + i][tx]);
    }
}

// ---------------- fused double RMSNorm: x f32 [8192,1024] -> xn1, xn2 bf16
__global__ __launch_bounds__(256) void rmsnorm2(const float* __restrict__ x,
    const float* __restrict__ g1, const float* __restrict__ g2,
    short* __restrict__ xn1, short* __restrict__ xn2) {
    int row = blockIdx.x;
    const float* xr = x + (size_t)row * DM;
    int t = threadIdx.x;
    float4 v = ((const float4*)xr)[t];
    float ss = v.x*v.x + v.y*v.y + v.z*v.z + v.w*v.w;
    #pragma unroll
    for (int off = 1; off < 64; off <<= 1) ss += __shfl_xor(ss, off);
    __shared__ float red[4];
    if ((t & 63) == 0) red[t >> 6] = ss;
    __syncthreads();
    float tot = red[0] + red[1] + red[2] + red[3];
    float rs = rsqrtf(tot * (1.0f / DM) + 1e-6f);
    float4 G1 = ((const float4*)g1)[t];
    float4 G2 = ((const float4*)g2)[t];
    union { short s[4]; int2 v; } o1, o2;
    o1.s[0] = f2bf(v.x * rs * G1.x); o1.s[1] = f2bf(v.y * rs * G1.y);
    o1.s[2] = f2bf(v.z * rs * G1.z); o1.s[3] = f2bf(v.w * rs * G1.w);
    o2.s[0] = f2bf(v.x * rs * G2.x); o2.s[1] = f2bf(v.y * rs * G2.y);
    o2.s[2] = f2bf(v.z * rs * G2.z); o2.s[3] = f2bf(v.w * rs * G2.w);
    *(int2*)(xn1 + (size_t)row * DM + t * 4) = o1.v;
    *(int2*)(xn2 + (size_t)row * DM + t * 4) = o2.v;
}

// ---------------- bf16 MFMA GEMM: A[M,K] bf16, Bt[N,K] bf16 (transposed), 128x128 tile, BK=64
// EPI: 0 = Cb = acc (bf16); 1 = Of = X + acc (f32); 2 = Cb = silu(acc) (bf16);
//      3 = Cb *= acc (bf16 RMW); 4 = Of += acc (f32 RMW)
template<int EPI>
__global__ __launch_bounds__(256) void gemm_bt(
    const short* __restrict__ A, const short* __restrict__ Bt,
    short* __restrict__ Cb, const float* __restrict__ X, float* __restrict__ Of,
    int M, int N, int K)
{
    __shared__ short As[128 * 64];
    __shared__ short Bs[128 * 64];
    int t = threadIdx.x;
    int wid = t >> 6, l = t & 63;
    int wm = wid >> 1, wn = wid & 1;

    int nwg = gridDim.x, bid = blockIdx.x;
    int wg = (bid & 7) * (nwg >> 3) + (bid >> 3);   // XCD swizzle (all grids %8==0)
    int tiles_n = N >> 7;
    int tm = wg / tiles_n, tn = wg % tiles_n;

    const short* Arow = A + (size_t)(tm * 128) * K;
    const short* Brow = Bt + (size_t)(tn * 128) * K;

    f32x4 acc[4][4];
    #pragma unroll
    for (int m = 0; m < 4; m++)
        #pragma unroll
        for (int n = 0; n < 4; n++) acc[m][n] = (f32x4){0.f, 0.f, 0.f, 0.f};

    for (int kt = 0; kt < K; kt += 64) {
        __syncthreads();
        #pragma unroll
        for (int i = 0; i < 4; i++) {
            int linear = i * 256 + t;         // 0..1023
            int row = linear >> 3;            // 0..127
            int slot = linear & 7;
            int srcslot = slot ^ (row & 7);   // pre-swizzled source, linear LDS dest
            gload_lds16(Arow + (size_t)row * K + kt + srcslot * 8, (char*)As + linear * 16);
            gload_lds16(Brow + (size_t)row * K + kt + srcslot * 8, (char*)Bs + linear * 16);
        }
        __syncthreads();
        #pragma unroll
        for (int ks = 0; ks < 2; ks++) {
            bf16x8 af[4], bfr[4];
            #pragma unroll
            for (int m = 0; m < 4; m++) {
                int row = wm * 64 + m * 16 + (l & 15);
                af[m] = *(const bf16x8*)((char*)As + row * 128 + ((ks * 64 + (l >> 4) * 16) ^ ((row & 7) << 4)));
            }
            #pragma unroll
            for (int n = 0; n < 4; n++) {
                int row = wn * 64 + n * 16 + (l & 15);
                bfr[n] = *(const bf16x8*)((char*)Bs + row * 128 + ((ks * 64 + (l >> 4) * 16) ^ ((row & 7) << 4)));
            }
            #pragma unroll
            for (int m = 0; m < 4; m++)
                #pragma unroll
                for (int n = 0; n < 4; n++)
                    acc[m][n] = __builtin_amdgcn_mfma_f32_16x16x32_bf16(af[m], bfr[n], acc[m][n], 0, 0, 0);
        }
    }

    #pragma unroll
    for (int m = 0; m < 4; m++)
        #pragma unroll
        for (int n = 0; n < 4; n++)
            #pragma unroll
            for (int r = 0; r < 4; r++) {
                int row = tm * 128 + wm * 64 + m * 16 + (l >> 4) * 4 + r;
                int col = tn * 128 + wn * 64 + n * 16 + (l & 15);
                size_t idx = (size_t)row * N + col;
                float v = acc[m][n][r];
                if constexpr (EPI == 0) Cb[idx] = f2bf(v);
                else if constexpr (EPI == 1) Of[idx] = X[idx] + v;
                else if constexpr (EPI == 2) Cb[idx] = f2bf(v * (1.f / (1.f + __expf(-v))));
                else if constexpr (EPI == 3) Cb[idx] = f2bf(bf2f(Cb[idx]) * v);
                else if constexpr (EPI == 4) Of[idx] += v;
            }
}

// ---------------- causal flash attention: qkv bf16 [B*T,3072] -> y bf16 [B*T,1024]
// 8 waves, 128 q rows per block, KV tile 64.
#define PSTR 76
__global__ __launch_bounds__(512, 4) void attn(const short* __restrict__ qkv, short* __restrict__ y) {
    __shared__ short Ks[64 * 64];      // [kv][d], swizzled
    __shared__ short Vt[64 * 64];      // [d][kv], swizzled
    __shared__ short Ps[8][16 * PSTR]; // per-wave P bounce
    int bh = blockIdx.y;
    int b = bh >> 4, h = bh & 15;
    int qt = (gridDim.x - 1) - blockIdx.x;     // reversed: long blocks first
    int t = threadIdx.x, wid = t >> 6, l = t & 63;
    const size_t base = (size_t)b * TT * 3072;
    int q0 = qt * 128 + wid * 16;

    bf16x8 qf[2];
    #pragma unroll
    for (int s = 0; s < 2; s++) {
        int row = q0 + (l & 15);
        qf[s] = *(const bf16x8*)(qkv + base + (size_t)row * 3072 + h * 64 + s * 32 + (l >> 4) * 8);
    }

    f32x4 o[4];
    #pragma unroll
    for (int n = 0; n < 4; n++) o[n] = (f32x4){0.f, 0.f, 0.f, 0.f};
    float m[4], ll[4];
    #pragma unroll
    for (int r = 0; r < 4; r++) { m[r] = -1e30f; ll[r] = 0.f; }

    // V transpose work assignment (t < 256): 2 rows x 8 d per thread
    int vrg = t >> 3;      // 0..31 (rows vrg*2, vrg*2+1)
    int vc  = t & 7;       // d-chunk (8 d's)

    int kend = qt * 128 + 128;
    for (int kb = 0; kb < kend; kb += 64) {
        __syncthreads();   // protect prev-iter LDS reads
        {
            // K tile: swizzled source -> linear LDS (async), 1 load per thread
            int row = t >> 3;          // 0..63
            int slot = t & 7;
            int srcslot = slot ^ (row & 7);
            gload_lds16(qkv + base + (size_t)(kb + row) * 3072 + 1024 + h * 64 + srcslot * 8,
                        (char*)Ks + t * 16);
        }
        if (t < 256) {
            // V tile: 2-row x 8-d micro transpose, packed b32 writes, (j^c)-mixed swizzle
            uint4 v0 = *(const uint4*)(qkv + base + (size_t)(kb + vrg * 2) * 3072 + 2048 + h * 64 + vc * 8);
            uint4 v1 = *(const uint4*)(qkv + base + (size_t)(kb + vrg * 2 + 1) * 3072 + 2048 + h * 64 + vc * 8);
            const short* s0 = (const short*)&v0;
            const short* s1 = (const short*)&v1;
            #pragma unroll
            for (int j = 0; j < 8; j++) {
                int d = vc * 8 + j;
                unsigned int pack = ((unsigned int)(unsigned short)s0[j]) |
                                    (((unsigned int)(unsigned short)s1[j]) << 16);
                int byte = (d * 128 + vrg * 4) ^ ((j ^ vc) << 4);
                *(unsigned int*)((char*)Vt + byte) = pack;
            }
        }
        __syncthreads();

        if (kb <= q0 + 15) {   // wave-uniform: skip fully-masked tiles
            // S = Q K^T  (rows=q, cols=kv)
            f32x4 s4[4];
            __builtin_amdgcn_s_setprio(1);
            #pragma unroll
            for (int j = 0; j < 4; j++) {
                f32x4 z = (f32x4){0.f, 0.f, 0.f, 0.f};
                #pragma unroll
                for (int ks = 0; ks < 2; ks++) {
                    int row = j * 16 + (l & 15);
                    bf16x8 kf = *(const bf16x8*)((char*)Ks + row * 128 + ((ks * 64 + (l >> 4) * 16) ^ ((row & 7) << 4)));
                    z = __builtin_amdgcn_mfma_f32_16x16x32_bf16(qf[ks], kf, z, 0, 0, 0);
                }
                s4[j] = z;
            }
            __builtin_amdgcn_s_setprio(0);
            bool diag = (kb + 63 > q0);
            #pragma unroll
            for (int j = 0; j < 4; j++)
                #pragma unroll
                for (int r = 0; r < 4; r++) {
                    float v = s4[j][r] * 0.125f;
                    if (diag) {
                        int qrow = q0 + (l >> 4) * 4 + r;
                        int kcol = kb + j * 16 + (l & 15);
                        if (kcol > qrow) v = -1e30f;
                    }
                    s4[j][r] = v;
                }

            // online softmax (row stats per reg r, reduced over 16-lane col groups)
            float alpha[4];
            #pragma unroll
            for (int r = 0; r < 4; r++) {
                float mx = fmaxf(fmaxf(s4[0][r], s4[1][r]), fmaxf(s4[2][r], s4[3][r]));
                #pragma unroll
                for (int off = 1; off < 16; off <<= 1) mx = fmaxf(mx, __shfl_xor(mx, off));
                float mn = fmaxf(m[r], mx);
                float a = __expf(m[r] - mn);
                float rs = 0.f;
                #pragma unroll
                for (int j = 0; j < 4; j++) {
                    float p = __expf(s4[j][r] - mn);
                    s4[j][r] = p;
                    rs += p;
                }
                #pragma unroll
                for (int off = 1; off < 16; off <<= 1) rs += __shfl_xor(rs, off);
                ll[r] = ll[r] * a + rs;
                m[r] = mn;
                alpha[r] = a;
            }
            #pragma unroll
            for (int n = 0; n < 4; n++)
                #pragma unroll
                for (int r = 0; r < 4; r++) o[n][r] *= alpha[r];

            // P -> LDS (wave-private, stride 76 = conflict-free), then PV
            short* P = &Ps[wid][0];
            #pragma unroll
            for (int j = 0; j < 4; j++)
                #pragma unroll
                for (int r = 0; r < 4; r++)
                    P[((l >> 4) * 4 + r) * PSTR + j * 16 + (l & 15)] = f2bf(s4[j][r]);

            bf16x8 pf[2];
            #pragma unroll
            for (int ks = 0; ks < 2; ks++)
                pf[ks] = *(const bf16x8*)(P + (l & 15) * PSTR + ks * 32 + (l >> 4) * 8);
            __builtin_amdgcn_s_setprio(1);
            #pragma unroll
            for (int n = 0; n < 4; n++) {
                #pragma unroll
                for (int ks = 0; ks < 2; ks++) {
                    int vrow = n * 16 + (l & 15);
                    int f = (vrow & 7) ^ ((vrow >> 3) & 7);
                    bf16x8 vf = *(const bf16x8*)((char*)Vt + vrow * 128 + ((ks * 64 + (l >> 4) * 16) ^ (f << 4)));
                    o[n] = __builtin_amdgcn_mfma_f32_16x16x32_bf16(pf[ks], vf, o[n], 0, 0, 0);
                }
            }
            __builtin_amdgcn_s_setprio(0);
        }
    }

    float inv[4];
    #pragma unroll
    for (int r = 0; r < 4; r++) inv[r] = 1.f / ll[r];
    #pragma unroll
    for (int n = 0; n < 4; n++)
        #pragma unroll
        for (int r = 0; r < 4; r++) {
            int row = q0 + (l >> 4) * 4 + r;
            int col = h * 64 + n * 16 + (l & 15);
            y[(size_t)(b * TT + row) * DM + col] = f2bf(o[n][r] * inv[r]);
        }
}

extern "C" void kernel_launch(void* const* d_in, const int* in_sizes, int n_in,
                              void* d_out, int out_size, void* d_ws, size_t ws_size,
                              hipStream_t stream) {
    (void)in_sizes; (void)n_in; (void)out_size; (void)ws_size;
    const float* x      = (const float*)d_in[0];
    const float* w_attn = (const float*)d_in[1];
    const float* w_proj = (const float*)d_in[2];
    const float* w1     = (const float*)d_in[3];
    const float* w2     = (const float*)d_in[4];
    const float* w3     = (const float*)d_in[5];
    const float* g1     = (const float*)d_in[6];
    const float* g2     = (const float*)d_in[7];
    float* out = (float*)d_out;

    char* ws = (char*)d_ws;
    size_t off = 0;
    auto alloc = [&](size_t bytes) { char* p = ws + off; off += (bytes + 255) & ~(size_t)255; return p; };
    short* wattn_t = (short*)alloc((size_t)3072 * 1024 * 2);
    short* wproj_t = (short*)alloc((size_t)1024 * 1024 * 2);
    short* w1t     = (short*)alloc((size_t)HPAD * 1024 * 2);
    short* w2t     = (short*)alloc((size_t)HPAD * 1024 * 2);
    short* w3t     = (short*)alloc((size_t)1024 * HPAD * 2);
    short* xn1     = (short*)alloc((size_t)8192 * 1024 * 2);
    short* xn2     = (short*)alloc((size_t)8192 * 1024 * 2);
    short* qkvb    = (short*)alloc((size_t)8192 * 3072 * 2);
    short* yb      = (short*)alloc((size_t)8192 * 1024 * 2);
    short* hb      = (short*)alloc((size_t)8192 * HPAD * 2);

    dim3 tb(32, 8);
    wprep<<<dim3(32, 96), tb, 0, stream>>>(w_attn, wattn_t, 1024, 3072, 1024, 3072);
    wprep<<<dim3(32, 32), tb, 0, stream>>>(w_proj, wproj_t, 1024, 1024, 1024, 1024);
    wprep<<<dim3(32, 88), tb, 0, stream>>>(w1, w1t, 1024, HID, 1024, HPAD);
    wprep<<<dim3(32, 88), tb, 0, stream>>>(w2, w2t, 1024, HID, 1024, HPAD);
    wprep<<<dim3(88, 32), tb, 0, stream>>>(w3, w3t, HID, 1024, HPAD, 1024);

    rmsnorm2<<<8192, 256, 0, stream>>>(x, g1, g2, xn1, xn2);

    gemm_bt<0><<<1536, 256, 0, stream>>>(xn1, wattn_t, qkvb, nullptr, nullptr, 8192, 3072, 1024);
    attn<<<dim3(16, 64), 512, 0, stream>>>(qkvb, yb);
    gemm_bt<1><<<512, 256, 0, stream>>>(yb, wproj_t, nullptr, x, out, 8192, 1024, 1024);
    gemm_bt<2><<<1408, 256, 0, stream>>>(xn2, w1t, hb, nullptr, nullptr, 8192, HPAD, 1024);
    gemm_bt<3><<<1408, 256, 0, stream>>>(xn2, w2t, hb, nullptr, nullptr, 8192, HPAD, 1024);
    gemm_bt<4><<<512, 256, 0, stream>>>(hb, w3t, nullptr, nullptr, out, 8192, 1024, HPAD);
}